// Round 5
// baseline (179.216 us; speedup 1.0000x reference)
//
#include <hip/hip_runtime.h>
#include <math.h>

#define VOCAB 50000
#define EMBED 128
#define SEQ   200
#define HID   30
#define BATCH 4096

// NUMERICS FROZEN (round-4 pass, absmax 0.0): the 200-step tanh recurrence
// amplifies per-step rounding ~1e5x (round-3 reassociation failed at 2.7e-2).
// Every FP op sequence below is bit-identical to round 4; only the h-value
// TRANSPORT changed (LDS round-trip -> v_readlane SGPR broadcast).
__device__ __forceinline__ float tanh_fast(float x) {
    // tanh(x) = 1 - 2/(e^{2x}+1); IEEE divide (NOT __fdividef - accuracy).
    float e = __expf(2.0f * x);
    return 1.0f - 2.0f / (e + 1.0f);
}

// wave-uniform broadcast of lane `lane`'s value (v_readlane -> SGPR)
__device__ __forceinline__ float bcast(float v, int lane) {
    return __int_as_float(__builtin_amdgcn_readlane(__float_as_int(v), lane));
}

// Kernel 1: embP[v][j] = sum_e emb[v][e] * Wx[e][j] + b_rnn[j]
// 8 groups of 32 lanes; each group does 8 vocab rows -> 64 rows/block.
// 8 independent loads per q-iter (x unroll 4 = 32 in flight) hides the
// same-address-load latency that bounded round 4; WxL LDS reads amortized x8.
// Per-(v,j) accumulation sequence identical to rounds 2/4.
__global__ __launch_bounds__(256) void embproj_kernel(
    const float* __restrict__ emb, const float* __restrict__ Wx,
    const float* __restrict__ brnn, float* __restrict__ embP)
{
    __shared__ float WxL[EMBED * HID];
    __shared__ float bL[32];
    int tid = threadIdx.x;
    for (int i = tid; i < EMBED * HID; i += 256) WxL[i] = Wx[i];
    if (tid < HID) bL[tid] = brnn[tid];
    __syncthreads();

    int g  = tid >> 5;
    int j  = tid & 31;
    int jj = (j < HID) ? j : 0;
    int v0 = blockIdx.x * 64 + g * 8;

    const float4* e[8];
    #pragma unroll
    for (int rr = 0; rr < 8; ++rr)
        e[rr] = (const float4*)(emb + (size_t)min(v0 + rr, VOCAB - 1) * EMBED);

    float bj = (j < HID) ? bL[jj] : 0.0f;
    float acc[8][4];
    #pragma unroll
    for (int rr = 0; rr < 8; ++rr) {
        acc[rr][0] = bj; acc[rr][1] = 0.f; acc[rr][2] = 0.f; acc[rr][3] = 0.f;
    }

    #pragma unroll 4
    for (int q = 0; q < EMBED / 4; ++q) {
        float4 rv[8];
        #pragma unroll
        for (int rr = 0; rr < 8; ++rr) rv[rr] = e[rr][q];
        #pragma unroll
        for (int d = 0; d < 4; ++d) {
            float w = WxL[(4 * q + d) * HID + jj];
            #pragma unroll
            for (int rr = 0; rr < 8; ++rr)
                acc[rr][d] += (&rv[rr].x)[d] * w;
        }
    }
    if (j < HID) {
        #pragma unroll
        for (int rr = 0; rr < 8; ++rr) {
            if (v0 + rr < VOCAB)
                embP[(size_t)(v0 + rr) * HID + j] =
                    (acc[rr][0] + acc[rr][1]) + (acc[rr][2] + acc[rr][3]);
        }
    }
}

// Kernel 2: fused RNN recurrence + dense head.
// 1 batch row per WAVE; h is broadcast per step via 30x v_readlane into
// SGPRs and consumed as the SGPR operand of v_fmac. LDS ops per step drop
// from 10 (8x ds_read_b128 + write + tok) to 1 (tok read) -- round 4 was
// LDS-pipe bound at ~1100 cyc/CU-step (one LDS unit serves all 4 SIMDs);
// the VALU pipe scales 4x per CU. FP sequence bit-identical to round 4.
__global__ __launch_bounds__(256, 4) void rnn_head_kernel(
    const int* __restrict__ tokens, const float* __restrict__ embP,
    const float* __restrict__ Wh,
    const float* __restrict__ W1, const float* __restrict__ b1,
    const float* __restrict__ W2, const float* __restrict__ b2,
    const float* __restrict__ W3, const float* __restrict__ b3,
    const float* __restrict__ Wo, const float* __restrict__ bo,
    float* __restrict__ out)
{
    __shared__ int   tokL[4][SEQ];
    __shared__ float d1L[4][128];
    __shared__ float d2L[4][64];

    int tid = threadIdx.x;
    int r   = tid >> 6;          // wave (= batch row) within block, 0..3
    int l   = tid & 63;
    int j   = l & 31;            // output column (lanes 32-63 mirror 0-31)
    int b   = blockIdx.x * 4 + r;

    // tokL[r] written and read only by wave r -> in-wave DS order, no barrier
    for (int i = l; i < SEQ; i += 64) tokL[r][i] = tokens[(size_t)b * SEQ + i];

    float whc[HID];
    #pragma unroll
    for (int k = 0; k < HID; ++k) whc[k] = (j < HID) ? Wh[k * HID + j] : 0.0f;

    bool ld = (l < HID);
    // prefetch ring: xq[s] holds xp for step t+s (8 loads in flight)
    float xq[8];
    #pragma unroll
    for (int s = 0; s < 8; ++s) {
        int tk = tokL[r][s];
        xq[s] = ld ? embP[(size_t)tk * HID + j] : 0.0f;
    }

    // hn: this lane's column value of h (lanes 30..63 compute benign zeros /
    // mirrors; only lanes 0..29 are ever readlane'd). h0 = 0.
    float hn = 0.0f;

    for (int t = 0; t < SEQ; t += 8) {
        #pragma unroll
        for (int s = 0; s < 8; ++s) {
            int tf = t + 8 + s; tf = (tf < SEQ) ? tf : SEQ - 1;
            int tk = tokL[r][tf];

            // two FMA chains (even k -> a0 seeded xp, odd k -> a1), exactly
            // the round-4 order; h[k] arrives as an SGPR via readlane.
            float a0 = xq[s], a1 = 0.0f;
            #pragma unroll
            for (int k = 0; k < HID; k += 2) {
                a0 += bcast(hn, k)     * whc[k];
                a1 += bcast(hn, k + 1) * whc[k + 1];
            }
            hn = tanh_fast(a0 + a1);
            // refill ring slot for step t+8+s
            xq[s] = ld ? embP[(size_t)tk * HID + j] : 0.0f;
        }
    }

    // final h broadcast once for the head (same values hL held in round 4)
    float hs[HID];
    #pragma unroll
    for (int k = 0; k < HID; ++k) hs[k] = bcast(hn, k);

    // ---- dense head: lanes 0-31, round-4 sequence exactly ----
    if (l < 32) {
        #pragma unroll
        for (int q = 0; q < 4; ++q) {
            int c = l + 32 * q;
            float acc = b1[c];
            #pragma unroll
            for (int k = 0; k < HID; ++k) acc += hs[k] * W1[k * 128 + c];
            d1L[r][c] = fmaxf(acc, 0.0f);
        }
        #pragma unroll
        for (int q = 0; q < 2; ++q) {
            int c = l + 32 * q;
            float acc = b2[c];
            #pragma unroll 8
            for (int k = 0; k < 128; ++k) acc += d1L[r][k] * W2[k * 64 + c];
            d2L[r][c] = fmaxf(acc, 0.0f);
        }
        float acc3 = b3[l];
        #pragma unroll 8
        for (int k = 0; k < 64; ++k) acc3 += d2L[r][k] * W3[k * 32 + l];
        acc3 = fmaxf(acc3, 0.0f);
        float prod = acc3 * Wo[l];
        #pragma unroll
        for (int m = 16; m > 0; m >>= 1) prod += __shfl_xor(prod, m, 32);
        if (l == 0) out[b] = 1.0f / (1.0f + __expf(-(prod + bo[0])));
    }
}

extern "C" void kernel_launch(void* const* d_in, const int* in_sizes, int n_in,
                              void* d_out, int out_size, void* d_ws, size_t ws_size,
                              hipStream_t stream) {
    (void)in_sizes; (void)n_in; (void)out_size; (void)ws_size;
    const int*   tokens = (const int*)  d_in[0];
    const float* emb    = (const float*)d_in[1];
    const float* Wx     = (const float*)d_in[2];
    const float* Wh     = (const float*)d_in[3];
    const float* brnn   = (const float*)d_in[4];
    const float* W1     = (const float*)d_in[5];
    const float* b1     = (const float*)d_in[6];
    const float* W2     = (const float*)d_in[7];
    const float* b2     = (const float*)d_in[8];
    const float* W3     = (const float*)d_in[9];
    const float* b3     = (const float*)d_in[10];
    const float* Wo     = (const float*)d_in[11];
    const float* bo     = (const float*)d_in[12];
    float* out  = (float*)d_out;
    float* embP = (float*)d_ws;   // 50000*30*4 = 6 MB

    embproj_kernel<<<(VOCAB + 63) / 64, 256, 0, stream>>>(emb, Wx, brnn, embP);
    rnn_head_kernel<<<BATCH / 4, 256, 0, stream>>>(
        tokens, embP, Wh, W1, b1, W2, b2, W3, b3, Wo, bo, out);
}

// Round 7
// 116.359 us; speedup vs baseline: 1.5402x; 1.5402x over previous
//
#include <hip/hip_runtime.h>
#include <math.h>

#define VOCAB 50000
#define EMBED 128
#define SEQ   200
#define HID   30
#define BATCH 4096

// NUMERICS FROZEN (round-4-structure pass, absmax 0.0). The 200-step tanh
// recurrence amplifies per-step rounding ~1e5x; every mapping change that
// altered the per-lane FP stream failed (r3 split-K 2.7e-2, r6 2-col 3.1e-2).
// This round: per-lane stream EXACTLY round 4's; only the LDS row base and
// the mirror-lane gating change (lanes 32-63 serve a real 2nd row).
__device__ __forceinline__ float tanh_fast(float x) {
    // tanh(x) = 1 - 2/(e^{2x}+1); IEEE divide (NOT __fdividef - accuracy).
    float e = __expf(2.0f * x);
    return 1.0f - 2.0f / (e + 1.0f);
}

// Kernel 1: embP[v][j] = sum_e emb[v][e] * Wx[e][j] + b_rnn[j]
// BYTE-IDENTICAL to the round-4 pass (121 us run). Do not touch.
__global__ __launch_bounds__(256) void embproj_kernel(
    const float* __restrict__ emb, const float* __restrict__ Wx,
    const float* __restrict__ brnn, float* __restrict__ embP)
{
    __shared__ float WxL[EMBED * HID];
    __shared__ float bL[32];
    int tid = threadIdx.x;
    for (int i = tid; i < EMBED * HID; i += 256) WxL[i] = Wx[i];
    if (tid < HID) bL[tid] = brnn[tid];
    __syncthreads();

    int g  = tid >> 5;
    int j  = tid & 31;
    int jj = (j < HID) ? j : 0;        // clamp LDS column for pad lanes
    int v0 = blockIdx.x * 32 + g * 4;

    int vr0 = min(v0 + 0, VOCAB - 1);
    int vr1 = min(v0 + 1, VOCAB - 1);
    int vr2 = min(v0 + 2, VOCAB - 1);
    int vr3 = min(v0 + 3, VOCAB - 1);
    const float4* e0 = (const float4*)(emb + (size_t)vr0 * EMBED);
    const float4* e1 = (const float4*)(emb + (size_t)vr1 * EMBED);
    const float4* e2 = (const float4*)(emb + (size_t)vr2 * EMBED);
    const float4* e3 = (const float4*)(emb + (size_t)vr3 * EMBED);

    float bj = (j < HID) ? bL[jj] : 0.0f;
    float acc[4][4];
    #pragma unroll
    for (int rr = 0; rr < 4; ++rr) {
        acc[rr][0] = bj; acc[rr][1] = 0.f; acc[rr][2] = 0.f; acc[rr][3] = 0.f;
    }

    #pragma unroll 4
    for (int q = 0; q < EMBED / 4; ++q) {
        float4 r0 = e0[q], r1 = e1[q], r2 = e2[q], r3 = e3[q];
        #pragma unroll
        for (int d = 0; d < 4; ++d) {
            float w = WxL[(4 * q + d) * HID + jj];
            acc[0][d] += (&r0.x)[d] * w;
            acc[1][d] += (&r1.x)[d] * w;
            acc[2][d] += (&r2.x)[d] * w;
            acc[3][d] += (&r3.x)[d] * w;
        }
    }
    if (j < HID) {
        #pragma unroll
        for (int rr = 0; rr < 4; ++rr) {
            if (v0 + rr < VOCAB)
                embP[(size_t)(v0 + rr) * HID + j] =
                    (acc[rr][0] + acc[rr][1]) + (acc[rr][2] + acc[rr][3]);
        }
    }
}

// Kernel 2: fused RNN recurrence + dense head.
// Wave = 2 batch rows x 32 lanes. Lane l: row = l>>5 (within wave), column
// j = l&31 -- the per-lane code is round 4's verbatim (same whc load, same
// ring-8 gather, same even/odd 15-FMA chains, same tanh, same head);
// round 4's redundant mirror lanes (32-63) now serve a real second row.
// The 8 ds_read_b128 h-broadcasts carry 2 distinct row addresses (2-way =
// free, m136); hL row stride 36 keeps h-writes at worst 2-way too.
// LDS instrs per CU-step: 16 waves x 10 (round 4) -> 8 waves x 10.
// All LDS traffic is wave-private -> no barriers anywhere.
__global__ __launch_bounds__(256, 2) void rnn_head_kernel(
    const int* __restrict__ tokens, const float* __restrict__ embP,
    const float* __restrict__ Wh,
    const float* __restrict__ W1, const float* __restrict__ b1,
    const float* __restrict__ W2, const float* __restrict__ b2,
    const float* __restrict__ W3, const float* __restrict__ b3,
    const float* __restrict__ Wo, const float* __restrict__ bo,
    float* __restrict__ out)
{
    __shared__ int tokL[8][SEQ];
    __shared__ __align__(16) float hL[8][36];   // stride 36: rows 2-way at worst
    __shared__ float d1L[8][128];
    __shared__ float d2L[8][64];

    int tid  = threadIdx.x;
    int wv   = tid >> 6;           // wave 0..3
    int l    = tid & 63;
    int half = l >> 5;             // row within wave, 0..1
    int j    = l & 31;             // column (exactly round 4's j = l&31)
    int rloc = wv * 2 + half;      // row within block, 0..7
    int b    = blockIdx.x * 8 + rloc;

    // stage this row's tokens (wave-private -> in-wave DS order, no barrier)
    for (int i = j; i < SEQ; i += 32)
        tokL[rloc][i] = tokens[(size_t)b * SEQ + i];

    hL[rloc][j] = 0.0f;            // h0 = 0, incl. pad cols 30,31 (stay 0)

    float whc[HID];
    #pragma unroll
    for (int k = 0; k < HID; ++k) whc[k] = (j < HID) ? Wh[k * HID + j] : 0.0f;

    bool ld = (j < HID);
    // prefetch ring: xq[s] holds xp for step t+s (8 loads in flight)
    float xq[8];
    #pragma unroll
    for (int s = 0; s < 8; ++s) {
        int tk = tokL[rloc][s];
        xq[s] = ld ? embP[(size_t)tk * HID + j] : 0.0f;
    }

    for (int t = 0; t < SEQ; t += 8) {
        #pragma unroll
        for (int s = 0; s < 8; ++s) {
            int tf = t + 8 + s; tf = (tf < SEQ) ? tf : SEQ - 1;
            int tkn = tokL[rloc][tf];

            // 8x ds_read_b128; 2 distinct row addresses per instr (free)
            float hv[32];
            const float4* h4 = (const float4*)(&hL[rloc][0]);
            #pragma unroll
            for (int qq = 0; qq < 8; ++qq) {
                float4 hh = h4[qq];
                hv[4*qq+0] = hh.x; hv[4*qq+1] = hh.y;
                hv[4*qq+2] = hh.z; hv[4*qq+3] = hh.w;
            }
            // round-4 chain verbatim: even k -> a0 (seeded xp), odd k -> a1
            float a0 = xq[s], a1 = 0.0f;
            #pragma unroll
            for (int k = 0; k < HID; k += 2) {
                a0 += hv[k]     * whc[k];
                a1 += hv[k + 1] * whc[k + 1];
            }
            float hn = tanh_fast(a0 + a1);
            if (j < HID) hL[rloc][j] = hn;   // cols 0..29 of this row
            // refill ring slot for step t+8+s
            xq[s] = ld ? embP[(size_t)tkn * HID + j] : 0.0f;
        }
    }

    // ---- dense head: round-4 code per 32-lane half, one row each ----
    {
        #pragma unroll
        for (int qq = 0; qq < 4; ++qq) {
            int c = j + 32 * qq;
            float acc = b1[c];
            #pragma unroll
            for (int k = 0; k < HID; ++k) acc += hL[rloc][k] * W1[k * 128 + c];
            d1L[rloc][c] = fmaxf(acc, 0.0f);
        }
        #pragma unroll
        for (int qq = 0; qq < 2; ++qq) {
            int c = j + 32 * qq;
            float acc = b2[c];
            #pragma unroll 8
            for (int k = 0; k < 128; ++k) acc += d1L[rloc][k] * W2[k * 64 + c];
            d2L[rloc][c] = fmaxf(acc, 0.0f);
        }
        float acc3 = b3[j];
        #pragma unroll 8
        for (int k = 0; k < 64; ++k) acc3 += d2L[rloc][k] * W3[k * 32 + j];
        acc3 = fmaxf(acc3, 0.0f);
        float prod = acc3 * Wo[j];
        #pragma unroll
        for (int m = 16; m > 0; m >>= 1) prod += __shfl_xor(prod, m, 32);
        if (j == 0) out[b] = 1.0f / (1.0f + __expf(-(prod + bo[0])));
    }
}

extern "C" void kernel_launch(void* const* d_in, const int* in_sizes, int n_in,
                              void* d_out, int out_size, void* d_ws, size_t ws_size,
                              hipStream_t stream) {
    (void)in_sizes; (void)n_in; (void)out_size; (void)ws_size;
    const int*   tokens = (const int*)  d_in[0];
    const float* emb    = (const float*)d_in[1];
    const float* Wx     = (const float*)d_in[2];
    const float* Wh     = (const float*)d_in[3];
    const float* brnn   = (const float*)d_in[4];
    const float* W1     = (const float*)d_in[5];
    const float* b1     = (const float*)d_in[6];
    const float* W2     = (const float*)d_in[7];
    const float* b2     = (const float*)d_in[8];
    const float* W3     = (const float*)d_in[9];
    const float* b3     = (const float*)d_in[10];
    const float* Wo     = (const float*)d_in[11];
    const float* bo     = (const float*)d_in[12];
    float* out  = (float*)d_out;
    float* embP = (float*)d_ws;   // 50000*30*4 = 6 MB

    embproj_kernel<<<(VOCAB + 31) / 32, 256, 0, stream>>>(emb, Wx, brnn, embP);
    rnn_head_kernel<<<BATCH / 8, 256, 0, stream>>>(
        tokens, embP, Wh, W1, b1, W2, b2, W3, b3, Wo, bo, out);
}